// Round 5
// baseline (298.053 us; speedup 1.0000x reference)
//
#include <hip/hip_runtime.h>

#define DEV static __device__ __forceinline__

typedef __attribute__((ext_vector_type(8))) short bf16x8;
typedef __attribute__((ext_vector_type(4))) float f32x4;

#define MFMA(a, b, c) __builtin_amdgcn_mfma_f32_16x16x32_bf16(a, b, c, 0, 0, 0)

DEV float bf2f(unsigned short h) { return __uint_as_float(((unsigned)h) << 16); }
DEV unsigned short f2bf(float f) {
  unsigned u = __float_as_uint(f);
  u += 0x7fffu + ((u >> 16) & 1u);
  return (unsigned short)(u >> 16);
}
DEV bf16x8 ld8(const unsigned short* p) { return *(const bf16x8*)p; }

DEV float dotg64(const float* x, const float* wrow) {
  const float4* wp = (const float4*)wrow;
  float a0 = 0.f, a1 = 0.f;
  #pragma unroll
  for (int c = 0; c < 8; ++c) {
    float4 u = wp[2*c], v = wp[2*c + 1];
    a0 = fmaf(u.x, x[8*c+0], a0); a0 = fmaf(u.y, x[8*c+1], a0);
    a0 = fmaf(u.z, x[8*c+2], a0); a0 = fmaf(u.w, x[8*c+3], a0);
    a1 = fmaf(v.x, x[8*c+4], a1); a1 = fmaf(v.y, x[8*c+5], a1);
    a1 = fmaf(v.z, x[8*c+6], a1); a1 = fmaf(v.w, x[8*c+7], a1);
  }
  return a0 + a1;
}
DEV float wred64(float v) {
  #pragma unroll
  for (int o = 32; o > 0; o >>= 1) v += __shfl_xor(v, o, 64);
  return v;
}

// d_ws layout (ushort element offsets): weights as bf16 hi/lo pairs
#define XW_HI 0
#define XW_LO 65536
#define OW_HI 131072
#define OW_LO 163840
#define MW_HI 196608
#define MW_LO 229376
#define AI_HI 262144
#define AI_LO 274432
#define SC_OFF 286720

// bf16 tiles: 80 rows x 64 cols, stride 64, XOR swizzle:
// elem(row,d) = (row<<6) + (d ^ ((row&7)<<3)). 80 = 5x16 exact MFMA tiles.

__global__ void prep_kernel(const float* __restrict__ xW, const float* __restrict__ oW,
                            const float* __restrict__ mW, const float* __restrict__ aiW,
                            const float* __restrict__ Ap, unsigned short* __restrict__ wsb) {
  const int gid = blockIdx.x * blockDim.x + threadIdx.x;
  const int stride = gridDim.x * blockDim.x;
  for (int i = gid; i < 65536; i += stride) {
    float x = xW[i]; unsigned short h = f2bf(x);
    wsb[XW_HI + i] = h; wsb[XW_LO + i] = f2bf(x - bf2f(h));
  }
  for (int i = gid; i < 32768; i += stride) {
    float x = oW[i]; unsigned short h = f2bf(x);
    wsb[OW_HI + i] = h; wsb[OW_LO + i] = f2bf(x - bf2f(h));
  }
  for (int i = gid; i < 32768; i += stride) {
    float x = mW[i]; unsigned short h = f2bf(x);
    wsb[MW_HI + i] = h; wsb[MW_LO + i] = f2bf(x - bf2f(h));
  }
  for (int i = gid; i < 12288; i += stride) {
    float x = aiW[i]; unsigned short h = f2bf(x);
    wsb[AI_HI + i] = h; wsb[AI_LO + i] = f2bf(x - bf2f(h));
  }
  float* sc = (float*)(wsb + SC_OFF);
  for (int i = gid; i < 512; i += stride) {
    int pi = i >> 6, d = i & 63;
    const float* a = Ap + (size_t)i * 16;
    float s1 = 0, s2 = 0, s3 = 0, s4 = 0;
    #pragma unroll
    for (int n = 0; n < 16; ++n) {
      float z = a[n]; float z2 = z * z;
      s1 += z; s2 += z2; s3 += z2 * z; s4 += z2 * z2;
    }
    sc[pi*256 + d]       = s1;
    sc[pi*256 + 64 + d]  = s2 * 0.5f;
    sc[pi*256 + 128 + d] = s3 * (1.f/6.f);
    sc[pi*256 + 192 + d] = s4 * (1.f/24.f);
  }
}

// R5: 512 threads / 2 rows / grid 512 = EXACTLY 2 blocks per CU, LDS 52,224 B
// (2x = 104,448 <= proven-resident 122,880 from R3) -> both blocks co-resident
// from t=0 -> ONE generation, wall ~= single-block latency.
// R0-R4 law: wall = generations x T_block; every prior config had >=2 gens.
// LDS cut via per-direction passes sharing ONE gate tile + ONE B tile
// (out_dir overwrites Bm_dir in place); merge accumulates in persistent regs
// across the two dir passes (identical FP summation order as fused merge).
// Phases keep <=4 weight frags live; relaxed (512,2) bounds -> natural regs
// ~100-115 (R1: 108) so 16 waves/CU also fit the 512-reg/SIMD file.
__global__ __launch_bounds__(512, 2)
void Mamba4CTRV8_kernel(
    const float* __restrict__ dense_x, const float* __restrict__ dense_W,
    const float* __restrict__ dense_b, const float* __restrict__ tbl,
    const float* __restrict__ cls, const float* __restrict__ ng,
    const float* __restrict__ nb, const float* __restrict__ xb,
    const float* __restrict__ Dp, const float* __restrict__ ob,
    const float* __restrict__ mb, const float* __restrict__ aib,
    const float* __restrict__ aoW, const float* __restrict__ aob,
    const float* __restrict__ w1, const float* __restrict__ b1,
    const float* __restrict__ w2, const float* __restrict__ b2,
    const float* __restrict__ w3, const float* __restrict__ b3,
    const int* __restrict__ sidx, const unsigned short* __restrict__ wsb,
    float* __restrict__ out) {
  __shared__ __align__(16) unsigned char smem[52224];
  float*          s_seq  = (float*)smem;                     // 80x64 f32 spine (20480); tail: V bf16 tile (first 10240)
  unsigned short* s_xnb  = (unsigned short*)(smem + 20480);  // 80x64 bf16 xn / final seq (10240)
  unsigned short* bG     = (unsigned short*)(smem + 30720);  // gates->scanout per dir (10240); tail: f32 scratch
  unsigned short* bB0    = (unsigned short*)(smem + 40960);  // Bm_dir -> out_dir (10240); tail: K
  float*          s_small= (float*)(smem + 51200);           // 256 f32: phase0 scratch / scan seg0 sums
  unsigned short* s_V    = (unsigned short*)smem;            // tail alias of s_seq
  float* g0f = (float*)bG;        // tail: per-row 720 f32 {probs320, q64, seq0_64, c64}
  float* g1f = ((float*)bG) + 1440;  // tail: per-row 512 f32 {aopart256, ao64, mlp1_128, mlp2_64}
  const float* scf = (const float*)(wsb + SC_OFF);

  const int tid = threadIdx.x, b = blockIdx.x;
  const int lane = tid & 63, wv = tid >> 6;  // wv 0..7
  const int arow = lane & 15;
  const int aq = (lane >> 4) * 8;
  const int rq = (lane >> 4) * 4;
  const int rq7 = rq & 7;
  const int swA = (arow & 7) << 3;
  const int aqs0 = aq ^ swA, aqs1 = (aq + 32) ^ swA;

  // ---------------- Phase 0: build seq for both rows ----------------
  {
    float* s_dx = s_small;               // [0..13) row0, [16..29) row1
    int* s_idx = (int*)(s_small + 32);   // 52 ints
    if (tid < 13) s_dx[tid] = dense_x[(b*2)*13 + tid];
    else if (tid >= 16 && tid < 29) s_dx[tid] = dense_x[(b*2+1)*13 + (tid-16)];
    if (tid >= 64 && tid < 116) {
      int s = tid - 64, br = s / 26, si = s - br*26;
      int v = sidx[(b*2+br)*26 + si];
      v = v < 0 ? 0 : (v > 10000 ? 10000 : v);
      s_idx[s] = v;
    }
    __syncthreads();
    if (tid < 128) s_seq[(tid>>6)*40*64 + (tid&63)] = cls[tid&63];
    {
      const int br = tid >> 8, j0 = tid & 255;
      float x[13];
      #pragma unroll
      for (int k = 0; k < 13; ++k) x[k] = s_dx[br*16 + k];
      for (int j = j0; j < 832; j += 256) {
        float acc = dense_b[j];
        #pragma unroll
        for (int k = 0; k < 13; ++k) acc = fmaf(x[k], dense_W[j*13 + k], acc);
        s_seq[(br*40 + 1 + (j >> 6)) * 64 + (j & 63)] = acc;
      }
    }
    for (int e = tid; e < 832; e += 512) {
      int br = e / 416, rem = e - br*416, s = rem >> 4, c = rem & 15;
      const float4* row = (const float4*)(tbl + ((size_t)(s*10001 + s_idx[br*26 + s]))*64);
      ((float4*)&s_seq[(br*40 + 14 + s) * 64])[c] = row[c];
    }
  }
  __syncthreads();

  // ---------------- 4 bidirectional mamba layers (dirs sequential, merge in regs) ----------------
  for (int L = 0; L < 4; ++L) {
    const int pi0 = 2*L;

    // LN: 80 tokens over 8 waves (two 32-lane halves per wave)
    {
      const int half = lane >> 5, dl = lane & 31;
      #pragma unroll 1
      for (int it = 0; it < 5; ++it) {
        int t = wv*10 + it*2 + half;  // 0..79
        int e = t*64 + dl;
        float x0 = s_seq[e], x1 = s_seq[e + 32];
        float s = x0 + x1, q = fmaf(x0, x0, x1*x1);
        #pragma unroll
        for (int o = 16; o > 0; o >>= 1) { s += __shfl_xor(s, o, 64); q += __shfl_xor(q, o, 64); }
        float mean = s * (1.f/64.f);
        float var = q * (1.f/64.f) - mean*mean;
        float rs = rsqrtf(var + 1e-5f);
        float xn0 = fmaf((x0 - mean) * rs, ng[pi0*64 + dl], nb[pi0*64 + dl]);
        float xn1 = fmaf((x1 - mean) * rs, ng[pi0*64 + dl + 32], nb[pi0*64 + dl + 32]);
        int sw = (t & 7) << 3;
        int eb = t << 6;
        s_xnb[eb + (dl ^ sw)] = f2bf(xn0);
        s_xnb[eb + ((dl + 32) ^ sw)] = f2bf(xn1);
      }
    }
    __syncthreads();

    // persistent merge accumulators (filled by merge-half after each dir)
    f32x4 mA = {0,0,0,0}, mB = {0,0,0,0}, mC = {0,0,0,0};
    const int n0m = (wv & 3)*16 + arow;
    const int mtbm = (wv < 4) ? 0 : 3;   // waves 0-3: mts {0,1,2}; 4-7: {3,4}
    const float bom = mb[L*64 + n0m];

    #pragma unroll 1
    for (int dr = 0; dr < 2; ++dr) {
      const int pi = pi0 + dr;

      // xproj(dir): wave w -> col j=w*16+arow (delta w<4 -> bG, Bm w>=4 -> bB0)
      {
        const int j = wv*16 + arow;
        const unsigned short* Wh = wsb + XW_HI + pi*8192 + j*64;
        const unsigned short* Wl = wsb + XW_LO + pi*8192 + j*64;
        bf16x8 bh0 = ld8(Wh + aq), bh1 = ld8(Wh + 32 + aq);
        bf16x8 bl0 = ld8(Wl + aq), bl1 = ld8(Wl + 32 + aq);
        const float bj = xb[pi*128 + j];
        const bool isDelta = (wv < 4);
        float c1=0,c2=0,c3=0,c4=0;
        if (isDelta) {
          c1=scf[pi*256+j]; c2=scf[pi*256+64+j]; c3=scf[pi*256+128+j]; c4=scf[pi*256+192+j];
        }
        for (int mt = 0; mt < 5; ++mt) {
          const unsigned short* A = s_xnb + ((mt*16 + arow) << 6);
          bf16x8 ah0 = ld8(A + aqs0), ah1 = ld8(A + aqs1);
          f32x4 a0 = {0,0,0,0};
          a0 = MFMA(ah0, bh0, a0); a0 = MFMA(ah0, bl0, a0);
          a0 = MFMA(ah1, bh1, a0); a0 = MFMA(ah1, bl1, a0);
          const int rbase = mt*16 + rq;
          #pragma unroll
          for (int r = 0; r < 4; ++r) {
            int row = rbase + r;  // 0..79 exact
            int swr = (rq7 + r) << 3;
            float xv = a0[r] + bj;
            if (isDelta) {
              float sp = fmaxf(xv, 0.f) + __logf(1.f + __expf(-fabsf(xv)));
              bG[(row << 6) + (j ^ swr)] =
                f2bf(sp * fmaf(sp, fmaf(sp, fmaf(sp, c4, c3), c2), c1));
            } else {
              bB0[(row << 6) + ((j - 64) ^ swr)] = f2bf(xv);
            }
          }
        }
      }
      __syncthreads();

      // scan(dir) pass1: 256 active threads, (row, seg, d); seg0 sums -> s_small
      {
        if (tid < 256) {
          const int d = tid & 63, seg = (tid >> 6) & 1, br2 = tid >> 7;
          const int base = br2*40;
          float run = 0.f;
          #pragma unroll
          for (int k = 0; k < 20; ++k) {
            int t = base + (dr ? (39 - (seg*20 + k)) : (seg*20 + k));
            int o = (t << 6) + (d ^ ((t & 7) << 3));
            run = fmaf(bf2f(s_xnb[o]), bf2f(bB0[o]), run);
          }
          if (seg == 0) s_small[br2*64 + d] = run;
        }
      }
      __syncthreads();
      // scan(dir) pass2: recompute with offset, write scanout into bG in place
      {
        if (tid < 256) {
          const int d = tid & 63, seg = (tid >> 6) & 1, br2 = tid >> 7;
          const int base = br2*40;
          const float off = seg ? s_small[br2*64 + d] : 0.f;
          const float dpd = Dp[pi*64 + d];
          float run = off;
          #pragma unroll
          for (int k = 0; k < 20; ++k) {
            int t = base + (dr ? (39 - (seg*20 + k)) : (seg*20 + k));
            int o = (t << 6) + (d ^ ((t & 7) << 3));
            float xn = bf2f(s_xnb[o]);
            run = fmaf(xn, bf2f(bB0[o]), run);
            float gate = 16.f + bf2f(bG[o]);
            bG[o] = f2bf(fmaf(run, gate, xn * dpd));
          }
        }
      }
      __syncthreads();

      // outproj(dir) + residual: out_dir overwrites bB0 (Bm dead after scan)
      {
        const int j = (wv & 3)*16 + arow;
        const int mt0 = (wv < 4) ? 0 : 3, mt1 = (wv < 4) ? 3 : 5;
        const unsigned short* Wh = wsb + OW_HI + pi*4096 + j*64;
        const unsigned short* Wl = wsb + OW_LO + pi*4096 + j*64;
        bf16x8 bh0 = ld8(Wh + aq), bh1 = ld8(Wh + 32 + aq);
        bf16x8 bl0 = ld8(Wl + aq), bl1 = ld8(Wl + 32 + aq);
        const float bo = ob[pi*64 + j];
        #pragma unroll 1
        for (int mt = mt0; mt < mt1; ++mt) {
          const unsigned short* A0 = bG + ((mt*16 + arow) << 6);
          bf16x8 a00 = ld8(A0 + aqs0), a01 = ld8(A0 + aqs1);
          f32x4 c0 = {0,0,0,0};
          c0 = MFMA(a00, bh0, c0); c0 = MFMA(a00, bl0, c0);
          c0 = MFMA(a01, bh1, c0); c0 = MFMA(a01, bl1, c0);
          const int rbase = mt*16 + rq;
          #pragma unroll
          for (int r = 0; r < 4; ++r) {
            int row = rbase + r;
            int o = (row << 6) + (j ^ ((rq7 + r) << 3));
            bB0[o] = f2bf(c0[r] + bo + s_seq[row*64 + j]);
          }
        }
      }
      __syncthreads();

      // merge-half(dir): accumulate out_dir @ MW[:, dir-half] into mA/mB/mC regs
      {
        const unsigned short* Wh = wsb + MW_HI + L*8192 + n0m*128 + dr*64;
        const unsigned short* Wl = wsb + MW_LO + L*8192 + n0m*128 + dr*64;
        bf16x8 w0 = ld8(Wh + aq), w1f = ld8(Wh + 32 + aq);
        bf16x8 v0 = ld8(Wl + aq), v1f = ld8(Wl + 32 + aq);
        const unsigned short* A0 = bB0 + (((mtbm + 0)*16 + arow) << 6);
        const unsigned short* A1 = bB0 + (((mtbm + 1)*16 + arow) << 6);
        bf16x8 h0 = ld8(A0 + aqs0), h1 = ld8(A0 + aqs1);
        mA = MFMA(h0, w0, mA); mA = MFMA(h0, v0, mA);
        mA = MFMA(h1, w1f, mA); mA = MFMA(h1, v1f, mA);
        h0 = ld8(A1 + aqs0); h1 = ld8(A1 + aqs1);
        mB = MFMA(h0, w0, mB); mB = MFMA(h0, v0, mB);
        mB = MFMA(h1, w1f, mB); mB = MFMA(h1, v1f, mB);
        if (wv < 4) {  // wave-uniform: third mt only for waves 0-3 (mt=2)
          const unsigned short* A2 = bB0 + ((2*16 + arow) << 6);
          h0 = ld8(A2 + aqs0); h1 = ld8(A2 + aqs1);
          mC = MFMA(h0, w0, mC); mC = MFMA(h0, v0, mC);
          mC = MFMA(h1, w1f, mC); mC = MFMA(h1, v1f, mC);
        }
      }
      __syncthreads();
    }

    // merge epilogue: write spine (and final bf16 seq + seq0 copy at L==3)
    {
      #define MERGE_EPI(ACC, MT) { const int rbase = (MT)*16 + rq;                   \
        _Pragma("unroll") for (int r = 0; r < 4; ++r) { int row = rbase + r;         \
          float v = ACC[r] + bom; s_seq[row*64 + n0m] = v;                           \
          if (L == 3) { s_xnb[(row << 6) + (n0m ^ ((rq7 + r) << 3))] = f2bf(v);      \
            if (row == 0) g0f[384 + n0m] = v;                                        \
            else if (row == 40) g0f[720 + 384 + n0m] = v; } } }
      MERGE_EPI(mA, mtbm)
      MERGE_EPI(mB, mtbm + 1)
      if (wv < 4) { MERGE_EPI(mC, 2) }
      #undef MERGE_EPI
    }
    __syncthreads();
  }

  // ---------------- Attention tail ----------------
  // QKV: 48 units (K/V: 8 ct x 5 mt; Q: 4 ct x mt{0,2}) over 8 waves = 6 each
  // K -> bB0 ; V -> s_V (s_seq area, dead after epilogue seq0 copy) ; Q -> g0f
  {
    #pragma unroll 1
    for (int i = 0; i < 6; ++i) {
      const int u = wv + 8*i;
      int j, mtk;
      if (u < 40) { j = 64 + (u & 7)*16 + arow; mtk = u >> 3; }
      else { int qi = u - 40; j = (qi & 3)*16 + arow; mtk = (qi >> 2) * 2; }
      const unsigned short* Wh = wsb + AI_HI + j*64;
      const unsigned short* Wl = wsb + AI_LO + j*64;
      bf16x8 bh0 = ld8(Wh + aq), bh1 = ld8(Wh + 32 + aq);
      bf16x8 bl0 = ld8(Wl + aq), bl1 = ld8(Wl + 32 + aq);
      const float bj = aib[j];
      const unsigned short* A = s_xnb + ((mtk*16 + arow) << 6);
      bf16x8 ah0 = ld8(A + aqs0), ah1 = ld8(A + aqs1);
      f32x4 a0 = {0,0,0,0};
      a0 = MFMA(ah0, bh0, a0); a0 = MFMA(ah0, bl0, a0);
      a0 = MFMA(ah1, bh1, a0); a0 = MFMA(ah1, bl1, a0);
      const int rbase = mtk*16 + rq;
      #pragma unroll
      for (int r = 0; r < 4; ++r) {
        int row = rbase + r;
        int swr = (rq7 + r) << 3;
        float val = a0[r] + bj;
        if (u < 40) {
          if (j < 128) bB0[(row << 6) + ((j - 64) ^ swr)] = f2bf(val);
          else         s_V[(row << 6) + ((j - 128) ^ swr)] = f2bf(val);
        } else {
          if (row == 0)       g0f[320 + j] = val;
          else if (row == 40) g0f[720 + 320 + j] = val;
        }
      }
    }
  }
  __syncthreads();

  // logits: 2 rows x 8 heads x 40 keys = 640
  for (int e = tid; e < 640; e += 512) {
    int br = e / 320, rem = e - br*320;
    int h = rem / 40, kk = rem - h*40;
    int row = br*40 + kk;
    int kbase = (row << 6) + ((h*8) ^ ((kk & 7) << 3));
    float acc = 0.f;
    #pragma unroll
    for (int i = 0; i < 8; ++i)
      acc += g0f[br*720 + 320 + h*8 + i] * bf2f(bB0[kbase + i]);
    g0f[br*720 + rem] = acc * 0.35355339059327373f;
  }
  __syncthreads();

  // softmax: 16 heads over 8 waves, 32 lanes per head
  {
    const int hh = wv*2 + (lane >> 5), jl = lane & 31;
    float* pr = g0f + (hh >> 3)*720 + (hh & 7)*40;
    float a = pr[jl];
    float bv = (jl < 8) ? pr[32 + jl] : -1e30f;
    float m = fmaxf(a, bv);
    #pragma unroll
    for (int o = 16; o > 0; o >>= 1) m = fmaxf(m, __shfl_xor(m, o, 32));
    float pa = __expf(a - m), pb = (jl < 8) ? __expf(bv - m) : 0.f;
    float s = pa + pb;
    #pragma unroll
    for (int o = 16; o > 0; o >>= 1) s += __shfl_xor(s, o, 32);
    float inv = 1.f / s;
    pr[jl] = pa * inv;
    if (jl < 8) pr[32 + jl] = pb * inv;
  }
  __syncthreads();

  // ao partials: 2 rows x 4 quarters x 64 d = 512
  {
    const int d = tid & 63, qrt = (tid >> 6) & 3, br = tid >> 8, hh = d >> 3;
    float acc = 0.f;
    #pragma unroll
    for (int k = qrt*10; k < qrt*10 + 10; ++k) {
      int o = ((br*40 + k) << 6) + (d ^ ((k & 7) << 3));
      acc += g0f[br*720 + hh*40 + k] * bf2f(s_V[o]);
    }
    g1f[br*512 + qrt*64 + d] = acc;
  }
  __syncthreads();
  if (tid < 128) {
    float* p = g1f + (tid >> 6)*512;
    int d = tid & 63;
    p[256 + d] = p[d] + p[64 + d] + p[128 + d] + p[192 + d];
  }
  __syncthreads();

  // c = seq0 + ao @ aoW.T + aob
  if (tid < 128) {
    int br = tid >> 6, o = tid & 63;
    g0f[br*720 + 448 + o] = g0f[br*720 + 384 + o] + aob[o]
                          + dotg64(&g1f[br*512 + 256], aoW + (size_t)o*64);
  }
  __syncthreads();

  // MLP1
  if (tid < 256) {
    int br = tid >> 7, o = tid & 127;
    g1f[br*512 + 320 + o] = fmaxf(b1[o] + dotg64(&g0f[br*720 + 448], w1 + (size_t)o*64), 0.f);
  }
  __syncthreads();

  // MLP2
  if (tid < 128) {
    int br = tid >> 6, o = tid & 63;
    float acc = dotg64(&g1f[br*512 + 320], w2 + (size_t)o*128)
              + dotg64(&g1f[br*512 + 384], w2 + (size_t)o*128 + 64);
    g1f[br*512 + 448 + o] = fmaxf(acc + b2[o], 0.f);
  }
  __syncthreads();

  if (tid < 128) {
    int br = tid >> 6;
    float v = g1f[br*512 + 448 + lane] * w3[lane];
    v = wred64(v);
    if (lane == 0) out[b*2 + br] = v + b3[0];
  }
}

extern "C" void kernel_launch(void* const* d_in, const int* in_sizes, int n_in,
                              void* d_out, int out_size, void* d_ws, size_t ws_size,
                              hipStream_t stream) {
  (void)n_in; (void)ws_size; (void)out_size;
  const float* dense_x = (const float*)d_in[0];
  const float* dense_W = (const float*)d_in[1];
  const float* dense_b = (const float*)d_in[2];
  const float* tbl     = (const float*)d_in[3];
  const float* cls     = (const float*)d_in[4];
  const float* ng      = (const float*)d_in[5];
  const float* nb      = (const float*)d_in[6];
  const float* xW      = (const float*)d_in[7];
  const float* xb      = (const float*)d_in[8];
  const float* Ap      = (const float*)d_in[9];
  const float* Dp      = (const float*)d_in[10];
  const float* oW      = (const float*)d_in[11];
  const float* ob      = (const float*)d_in[12];
  const float* mW      = (const float*)d_in[13];
  const float* mb      = (const float*)d_in[14];
  const float* aiW     = (const float*)d_in[15];
  const float* aib     = (const float*)d_in[16];
  const float* aoW     = (const float*)d_in[17];
  const float* aob     = (const float*)d_in[18];
  const float* w1      = (const float*)d_in[19];
  const float* b1      = (const float*)d_in[20];
  const float* w2      = (const float*)d_in[21];
  const float* b2      = (const float*)d_in[22];
  const float* w3      = (const float*)d_in[23];
  const float* b3      = (const float*)d_in[24];
  const int*   sidx    = (const int*)d_in[25];
  float* out = (float*)d_out;
  unsigned short* wsb = (unsigned short*)d_ws;

  hipLaunchKernelGGL(prep_kernel, dim3(256), dim3(256), 0, stream,
                     xW, oW, mW, aiW, Ap, wsb);

  const int B = in_sizes[0] / 13;  // 1024
  hipLaunchKernelGGL(Mamba4CTRV8_kernel, dim3(B/2), dim3(512), 0, stream,
                     dense_x, dense_W, dense_b, tbl, cls, ng, nb, xb, Dp, ob, mb,
                     aib, aoW, aob, w1, b1, w2, b2, w3, b3, sidx, wsb, out);
}

// Round 6
// 251.363 us; speedup vs baseline: 1.1857x; 1.1857x over previous
//
#include <hip/hip_runtime.h>

#define DEV static __device__ __forceinline__

typedef __attribute__((ext_vector_type(8))) short bf16x8;
typedef __attribute__((ext_vector_type(4))) float f32x4;

#define MFMA(a, b, c) __builtin_amdgcn_mfma_f32_16x16x32_bf16(a, b, c, 0, 0, 0)

DEV float bf2f(unsigned short h) { return __uint_as_float(((unsigned)h) << 16); }
DEV unsigned short f2bf(float f) {
  unsigned u = __float_as_uint(f);
  u += 0x7fffu + ((u >> 16) & 1u);
  return (unsigned short)(u >> 16);
}
DEV bf16x8 ld8(const unsigned short* p) { return *(const bf16x8*)p; }

DEV float dotg64(const float* x, const float* wrow) {
  const float4* wp = (const float4*)wrow;
  float a0 = 0.f, a1 = 0.f;
  #pragma unroll
  for (int c = 0; c < 8; ++c) {
    float4 u = wp[2*c], v = wp[2*c + 1];
    a0 = fmaf(u.x, x[8*c+0], a0); a0 = fmaf(u.y, x[8*c+1], a0);
    a0 = fmaf(u.z, x[8*c+2], a0); a0 = fmaf(u.w, x[8*c+3], a0);
    a1 = fmaf(v.x, x[8*c+4], a1); a1 = fmaf(v.y, x[8*c+5], a1);
    a1 = fmaf(v.z, x[8*c+6], a1); a1 = fmaf(v.w, x[8*c+7], a1);
  }
  return a0 + a1;
}
DEV float wred64(float v) {
  #pragma unroll
  for (int o = 32; o > 0; o >>= 1) v += __shfl_xor(v, o, 64);
  return v;
}

// d_ws layout (ushort element offsets): weights as bf16 hi/lo pairs
#define XW_HI 0
#define XW_LO 65536
#define OW_HI 131072
#define OW_LO 163840
#define MW_HI 196608
#define MW_LO 229376
#define AI_HI 262144
#define AI_LO 274432
#define SC_OFF 286720

// bf16 tiles: 160 rows x 64 cols, stride 64, XOR swizzle:
// elem(row,d) = (row<<6) + (d ^ ((row&7)<<3)). 160 = 10x16 exact MFMA tiles,
// and 40 | 8 so (row&7) == (token-within-batch-row & 7) everywhere.

__global__ void prep_kernel(const float* __restrict__ xW, const float* __restrict__ oW,
                            const float* __restrict__ mW, const float* __restrict__ aiW,
                            const float* __restrict__ Ap, unsigned short* __restrict__ wsb) {
  const int gid = blockIdx.x * blockDim.x + threadIdx.x;
  const int stride = gridDim.x * blockDim.x;
  for (int i = gid; i < 65536; i += stride) {
    float x = xW[i]; unsigned short h = f2bf(x);
    wsb[XW_HI + i] = h; wsb[XW_LO + i] = f2bf(x - bf2f(h));
  }
  for (int i = gid; i < 32768; i += stride) {
    float x = oW[i]; unsigned short h = f2bf(x);
    wsb[OW_HI + i] = h; wsb[OW_LO + i] = f2bf(x - bf2f(h));
  }
  for (int i = gid; i < 32768; i += stride) {
    float x = mW[i]; unsigned short h = f2bf(x);
    wsb[MW_HI + i] = h; wsb[MW_LO + i] = f2bf(x - bf2f(h));
  }
  for (int i = gid; i < 12288; i += stride) {
    float x = aiW[i]; unsigned short h = f2bf(x);
    wsb[AI_HI + i] = h; wsb[AI_LO + i] = f2bf(x - bf2f(h));
  }
  float* sc = (float*)(wsb + SC_OFF);
  for (int i = gid; i < 512; i += stride) {
    int pi = i >> 6, d = i & 63;
    const float* a = Ap + (size_t)i * 16;
    float s1 = 0, s2 = 0, s3 = 0, s4 = 0;
    #pragma unroll
    for (int n = 0; n < 16; ++n) {
      float z = a[n]; float z2 = z * z;
      s1 += z; s2 += z2; s3 += z2 * z; s4 += z2 * z2;
    }
    sc[pi*256 + d]       = s1;
    sc[pi*256 + 64 + d]  = s2 * 0.5f;
    sc[pi*256 + 128 + d] = s3 * (1.f/6.f);
    sc[pi*256 + 192 + d] = s4 * (1.f/24.f);
  }
}

// R6: FOUR batch rows per 512-thread block, grid = 256 = one block per CU =
// SINGLE GENERATION by construction (LDS 145,408 B hard-caps residency at 1;
// no scheduler behavior can add a 2nd generation: 256 blocks -> 1:1 on CUs).
// R0-R5 ledger law: wall = generations x T_block, and T_block is latency-
// dominated (512thr/2row: 72us; 256thr/1row: 82us -> 4x work costs ~nothing).
// So: double work-per-block again, gens 2 -> 1. Also: 160 tokens = exactly
// 10 MFMA tiles (no pads/guards) and the scan becomes single-pass (512
// streams = 1/thread, no seg-split recompute, one barrier fewer per dir).
__global__ __launch_bounds__(512, 2)
void Mamba4CTRV9_kernel(
    const float* __restrict__ dense_x, const float* __restrict__ dense_W,
    const float* __restrict__ dense_b, const float* __restrict__ tbl,
    const float* __restrict__ cls, const float* __restrict__ ng,
    const float* __restrict__ nb, const float* __restrict__ xb,
    const float* __restrict__ Dp, const float* __restrict__ ob,
    const float* __restrict__ mb, const float* __restrict__ aib,
    const float* __restrict__ aoW, const float* __restrict__ aob,
    const float* __restrict__ w1, const float* __restrict__ b1,
    const float* __restrict__ w2, const float* __restrict__ b2,
    const float* __restrict__ w3, const float* __restrict__ b3,
    const int* __restrict__ sidx, const unsigned short* __restrict__ wsb,
    float* __restrict__ out) {
  __shared__ __align__(16) unsigned char smem[145408];
  float*          s_seq  = (float*)smem;                      // 160x64 f32 spine (40960)
  unsigned short* s_xnb  = (unsigned short*)(smem + 40960);   // 160x64 bf16 xn / final seq (20480)
  unsigned short* bG0    = (unsigned short*)(smem + 61440);   // gate0->scanout0 ; tail f32 g0f
  unsigned short* bG1    = (unsigned short*)(smem + 81920);   // gate1->scanout1 ; tail f32 g1f
  unsigned short* bB0    = (unsigned short*)(smem + 102400);  // Bm0->out0 ; tail: K
  unsigned short* bB1    = (unsigned short*)(smem + 122880);  // Bm1->out1 ; tail: V
  float*          s_small= (float*)(smem + 143360);           // 512 f32: phase0 scratch
  float* g0f = (float*)bG0;          // tail: per-row 720 f32 {probs320, q64, seq0_64, c64} x4
  float* g1f = (float*)bG1;          // tail: per-row 512 f32 {aopart256, ao64, mlp1_128, mlp2_64} x4
  const float* scf = (const float*)(wsb + SC_OFF);

  const int tid = threadIdx.x, b = blockIdx.x;
  const int lane = tid & 63, wv = tid >> 6;  // wv 0..7
  const int arow = lane & 15;
  const int aq = (lane >> 4) * 8;
  const int rq = (lane >> 4) * 4;
  const int rq7 = rq & 7;
  const int swA = (arow & 7) << 3;
  const int aqs0 = aq ^ swA, aqs1 = (aq + 32) ^ swA;

  // ---------------- Phase 0: build seq for 4 rows ----------------
  {
    float* s_dx = s_small;               // 64 f32: br*16+k (k<13)
    int* s_idx = (int*)(s_small + 64);   // 104 ints
    if (tid < 64) {
      int br = tid >> 4, k = tid & 15;
      if (k < 13) s_dx[tid] = dense_x[(b*4 + br)*13 + k];
    }
    if (tid >= 64 && tid < 168) {
      int s = tid - 64, br = s / 26, si = s - br*26;
      int v = sidx[(b*4 + br)*26 + si];
      v = v < 0 ? 0 : (v > 10000 ? 10000 : v);
      s_idx[s] = v;
    }
    __syncthreads();
    if (tid < 256) s_seq[(tid >> 6)*40*64 + (tid & 63)] = cls[tid & 63];
    {
      const int br = tid >> 7, j0 = tid & 127;
      float x[13];
      #pragma unroll
      for (int k = 0; k < 13; ++k) x[k] = s_dx[br*16 + k];
      for (int j = j0; j < 832; j += 128) {
        float acc = dense_b[j];
        #pragma unroll
        for (int k = 0; k < 13; ++k) acc = fmaf(x[k], dense_W[j*13 + k], acc);
        s_seq[(br*40 + 1 + (j >> 6))*64 + (j & 63)] = acc;
      }
    }
    for (int e = tid; e < 1664; e += 512) {
      int br = e / 416, rem = e - br*416, s = rem >> 4, c = rem & 15;
      const float4* row = (const float4*)(tbl + ((size_t)(s*10001 + s_idx[br*26 + s]))*64);
      ((float4*)&s_seq[(br*40 + 14 + s)*64])[c] = row[c];
    }
  }
  __syncthreads();

  // ---------------- 4 bidirectional mamba layers (dirs fused, no guards) ----------------
  for (int L = 0; L < 4; ++L) {
    const int pi0 = 2*L, pi1 = 2*L + 1;

    // LN: 160 tokens over 8 waves x 2 halves x 10 iters
    {
      const int half = lane >> 5, dl = lane & 31;
      const float ng0 = ng[pi0*64 + dl], ng1 = ng[pi0*64 + dl + 32];
      const float nb0 = nb[pi0*64 + dl], nb1 = nb[pi0*64 + dl + 32];
      #pragma unroll 1
      for (int it = 0; it < 10; ++it) {
        int t = wv*20 + it*2 + half;  // 0..159
        int e = t*64 + dl;
        float x0 = s_seq[e], x1 = s_seq[e + 32];
        float s = x0 + x1, q = fmaf(x0, x0, x1*x1);
        #pragma unroll
        for (int o = 16; o > 0; o >>= 1) { s += __shfl_xor(s, o, 64); q += __shfl_xor(q, o, 64); }
        float mean = s * (1.f/64.f);
        float var = q * (1.f/64.f) - mean*mean;
        float rs = rsqrtf(var + 1e-5f);
        float xn0 = fmaf((x0 - mean) * rs, ng0, nb0);
        float xn1 = fmaf((x1 - mean) * rs, ng1, nb1);
        int sw = (t & 7) << 3;
        int eb = t << 6;
        s_xnb[eb + (dl ^ sw)] = f2bf(xn0);
        s_xnb[eb + ((dl + 32) ^ sw)] = f2bf(xn1);
      }
    }
    __syncthreads();

    // xproj both dirs fused: wave w -> col j (delta w<4 -> bG*, Bm w>=4 -> bB*), 10 mt
    {
      const int j = wv*16 + arow;  // 0..127
      const unsigned short* Wh0 = wsb + XW_HI + pi0*8192 + j*64;
      const unsigned short* Wl0 = wsb + XW_LO + pi0*8192 + j*64;
      const unsigned short* Wh1 = wsb + XW_HI + pi1*8192 + j*64;
      const unsigned short* Wl1 = wsb + XW_LO + pi1*8192 + j*64;
      bf16x8 bh00 = ld8(Wh0 + aq), bh01 = ld8(Wh0 + 32 + aq);
      bf16x8 bl00 = ld8(Wl0 + aq), bl01 = ld8(Wl0 + 32 + aq);
      bf16x8 bh10 = ld8(Wh1 + aq), bh11 = ld8(Wh1 + 32 + aq);
      bf16x8 bl10 = ld8(Wl1 + aq), bl11 = ld8(Wl1 + 32 + aq);
      const float bj0 = xb[pi0*128 + j], bj1 = xb[pi1*128 + j];
      const bool isDelta = (wv < 4);  // wave-uniform
      float c10=0,c20=0,c30=0,c40=0,c11=0,c21=0,c31=0,c41=0;
      if (isDelta) {
        c10=scf[pi0*256+j]; c20=scf[pi0*256+64+j]; c30=scf[pi0*256+128+j]; c40=scf[pi0*256+192+j];
        c11=scf[pi1*256+j]; c21=scf[pi1*256+64+j]; c31=scf[pi1*256+128+j]; c41=scf[pi1*256+192+j];
      }
      #pragma unroll 1
      for (int mt = 0; mt < 10; ++mt) {
        const unsigned short* A = s_xnb + ((mt*16 + arow) << 6);
        bf16x8 ah0 = ld8(A + aqs0), ah1 = ld8(A + aqs1);
        f32x4 a0 = {0,0,0,0}, a1 = {0,0,0,0};
        a0 = MFMA(ah0, bh00, a0); a0 = MFMA(ah0, bl00, a0);
        a0 = MFMA(ah1, bh01, a0); a0 = MFMA(ah1, bl01, a0);
        a1 = MFMA(ah0, bh10, a1); a1 = MFMA(ah0, bl10, a1);
        a1 = MFMA(ah1, bh11, a1); a1 = MFMA(ah1, bl11, a1);
        const int rbase = mt*16 + rq;
        #pragma unroll
        for (int r = 0; r < 4; ++r) {
          int row = rbase + r;  // 0..159 exact
          int swr = (rq7 + r) << 3;
          float x0v = a0[r] + bj0, x1v = a1[r] + bj1;
          if (isDelta) {
            float sp0 = fmaxf(x0v, 0.f) + __logf(1.f + __expf(-fabsf(x0v)));
            float sp1 = fmaxf(x1v, 0.f) + __logf(1.f + __expf(-fabsf(x1v)));
            int o = (row << 6) + (j ^ swr);
            bG0[o] = f2bf(sp0 * fmaf(sp0, fmaf(sp0, fmaf(sp0, c40, c30), c20), c10));
            bG1[o] = f2bf(sp1 * fmaf(sp1, fmaf(sp1, fmaf(sp1, c41, c31), c21), c11));
          } else {
            int o = (row << 6) + ((j - 64) ^ swr);
            bB0[o] = f2bf(x0v);
            bB1[o] = f2bf(x1v);
          }
        }
      }
    }
    __syncthreads();

    // Scan: SINGLE PASS. 512 streams (br,dir,d) = exactly 1 per thread, 40 steps.
    {
      const int d = tid & 63, dir = (tid >> 6) & 1, br = tid >> 7;  // br 0..3
      const unsigned short* bmb = dir ? bB1 : bB0;
      unsigned short* gb = dir ? bG1 : bG0;
      const float dpd = Dp[(pi0 + dir)*64 + d];
      const int base = br*40;
      float run = 0.f;
      #pragma unroll
      for (int k = 0; k < 40; ++k) {
        int t = base + (dir ? (39 - k) : k);
        int o = (t << 6) + (d ^ ((t & 7) << 3));
        float xn = bf2f(s_xnb[o]);
        run = fmaf(xn, bf2f(bmb[o]), run);
        float gate = 16.f + bf2f(gb[o]);
        gb[o] = f2bf(fmaf(run, gate, xn * dpd));
      }
    }
    __syncthreads();

    // outproj both dirs + residual: 4 col-tiles x 10 mt (5/5 wave-half split)
    {
      const int j = (wv & 3)*16 + arow;
      const int mt0 = (wv < 4) ? 0 : 5, mt1 = (wv < 4) ? 5 : 10;
      const unsigned short* Wh0 = wsb + OW_HI + pi0*4096 + j*64;
      const unsigned short* Wl0 = wsb + OW_LO + pi0*4096 + j*64;
      const unsigned short* Wh1 = wsb + OW_HI + pi1*4096 + j*64;
      const unsigned short* Wl1 = wsb + OW_LO + pi1*4096 + j*64;
      bf16x8 bh00 = ld8(Wh0 + aq), bh01 = ld8(Wh0 + 32 + aq);
      bf16x8 bl00 = ld8(Wl0 + aq), bl01 = ld8(Wl0 + 32 + aq);
      bf16x8 bh10 = ld8(Wh1 + aq), bh11 = ld8(Wh1 + 32 + aq);
      bf16x8 bl10 = ld8(Wl1 + aq), bl11 = ld8(Wl1 + 32 + aq);
      const float bo0 = ob[pi0*64 + j], bo1 = ob[pi1*64 + j];
      #pragma unroll 1
      for (int mt = mt0; mt < mt1; ++mt) {
        const unsigned short* A0 = bG0 + ((mt*16 + arow) << 6);
        const unsigned short* A1 = bG1 + ((mt*16 + arow) << 6);
        bf16x8 a00 = ld8(A0 + aqs0), a01 = ld8(A0 + aqs1);
        bf16x8 a10 = ld8(A1 + aqs0), a11 = ld8(A1 + aqs1);
        f32x4 c0 = {0,0,0,0}, c1 = {0,0,0,0};
        c0 = MFMA(a00, bh00, c0); c0 = MFMA(a00, bl00, c0);
        c0 = MFMA(a01, bh01, c0); c0 = MFMA(a01, bl01, c0);
        c1 = MFMA(a10, bh10, c1); c1 = MFMA(a10, bl10, c1);
        c1 = MFMA(a11, bh11, c1); c1 = MFMA(a11, bl11, c1);
        const int rbase = mt*16 + rq;
        #pragma unroll
        for (int r = 0; r < 4; ++r) {
          int row = rbase + r;
          int o = (row << 6) + (j ^ ((rq7 + r) << 3));
          float res = s_seq[row*64 + j];
          bB0[o] = f2bf(c0[r] + bo0 + res);
          bB1[o] = f2bf(c1[r] + bo1 + res);
        }
      }
    }
    __syncthreads();

    // merge: 4 col-tiles x 10 mt (5/5 wave-half split)
    {
      const int n0 = (wv & 3)*16 + arow;
      const int mt0 = (wv < 4) ? 0 : 5, mt1 = (wv < 4) ? 5 : 10;
      const unsigned short* Wh = wsb + MW_HI + L*8192 + n0*128;
      const unsigned short* Wl = wsb + MW_LO + L*8192 + n0*128;
      bf16x8 bh[4], bl[4];
      #pragma unroll
      for (int ks = 0; ks < 4; ++ks) { bh[ks] = ld8(Wh + ks*32 + aq); bl[ks] = ld8(Wl + ks*32 + aq); }
      const float bo = mb[L*64 + n0];
      #pragma unroll 1
      for (int mt = mt0; mt < mt1; ++mt) {
        const unsigned short* Af = bB0 + ((mt*16 + arow) << 6);
        const unsigned short* Ar = bB1 + ((mt*16 + arow) << 6);
        bf16x8 fh0 = ld8(Af + aqs0), fh1 = ld8(Af + aqs1);
        bf16x8 rh0 = ld8(Ar + aqs0), rh1 = ld8(Ar + aqs1);
        f32x4 a0 = {0,0,0,0};
        a0 = MFMA(fh0, bh[0], a0); a0 = MFMA(fh0, bl[0], a0);
        a0 = MFMA(fh1, bh[1], a0); a0 = MFMA(fh1, bl[1], a0);
        a0 = MFMA(rh0, bh[2], a0); a0 = MFMA(rh0, bl[2], a0);
        a0 = MFMA(rh1, bh[3], a0); a0 = MFMA(rh1, bl[3], a0);
        const int rbase = mt*16 + rq;
        #pragma unroll
        for (int r = 0; r < 4; ++r) {
          int row = rbase + r;
          float v = a0[r] + bo;
          s_seq[row*64 + n0] = v;
          if (L == 3) s_xnb[(row << 6) + (n0 ^ ((rq7 + r) << 3))] = f2bf(v);
        }
      }
    }
    __syncthreads();
  }

  // ---------------- Attention tail ----------------
  // QKV: 96 units (K/V: 8 ct x 10 mt = 80; Q: 4 ct x 4 mt{0,2,5,7} = 16) over 8 waves = 12 each
  {
    #pragma unroll 1
    for (int i = 0; i < 12; ++i) {
      const int u = wv + 8*i;  // 0..95
      int j, mtk;
      if (u < 80) { j = 64 + (u & 7)*16 + arow; mtk = u >> 3; }
      else {
        int qi = u - 80;                 // 0..15
        j = (qi & 3)*16 + arow;
        int p = qi >> 2;                 // 0..3
        mtk = p*2 + (p >> 1);            // {0,2,5,7}
      }
      const unsigned short* Wh = wsb + AI_HI + j*64;
      const unsigned short* Wl = wsb + AI_LO + j*64;
      bf16x8 bh0 = ld8(Wh + aq), bh1 = ld8(Wh + 32 + aq);
      bf16x8 bl0 = ld8(Wl + aq), bl1 = ld8(Wl + 32 + aq);
      const float bj = aib[j];
      const unsigned short* A = s_xnb + ((mtk*16 + arow) << 6);
      bf16x8 ah0 = ld8(A + aqs0), ah1 = ld8(A + aqs1);
      f32x4 a0 = {0,0,0,0};
      a0 = MFMA(ah0, bh0, a0); a0 = MFMA(ah0, bl0, a0);
      a0 = MFMA(ah1, bh1, a0); a0 = MFMA(ah1, bl1, a0);
      const int rbase = mtk*16 + rq;
      #pragma unroll
      for (int r = 0; r < 4; ++r) {
        int row = rbase + r;
        int swr = (rq7 + r) << 3;
        float val = a0[r] + bj;
        if (u < 80) {
          if (j < 128) bB0[(row << 6) + ((j - 64) ^ swr)] = f2bf(val);   // K
          else         bB1[(row << 6) + ((j - 128) ^ swr)] = f2bf(val);  // V
        } else {
          if (row % 40 == 0) g0f[(row/40)*720 + 320 + j] = val;          // q per batch-row
        }
      }
    }
    if (tid < 256) g0f[(tid >> 6)*720 + 384 + (tid & 63)] = s_seq[(tid >> 6)*40*64 + (tid & 63)];
  }
  __syncthreads();

  // logits: 4 rows x 8 heads x 40 keys = 1280
  for (int e = tid; e < 1280; e += 512) {
    int br = e / 320, rem = e - br*320;
    int h = rem / 40, kk = rem - h*40;
    int row = br*40 + kk;
    int kbase = (row << 6) + ((h*8) ^ ((kk & 7) << 3));
    float acc = 0.f;
    #pragma unroll
    for (int i = 0; i < 8; ++i)
      acc += g0f[br*720 + 320 + h*8 + i] * bf2f(bB0[kbase + i]);
    g0f[br*720 + rem] = acc * 0.35355339059327373f;
  }
  __syncthreads();

  // softmax: 32 heads over 8 waves, 16 lanes per head (40 keys = 16+16+8)
  {
    const int hh = wv*4 + (lane >> 4), jl = lane & 15;
    float* pr = g0f + (hh >> 3)*720 + (hh & 7)*40;
    float a = pr[jl];
    float bv = pr[16 + jl];
    float cv = (jl < 8) ? pr[32 + jl] : -1e30f;
    float m = fmaxf(fmaxf(a, bv), cv);
    #pragma unroll
    for (int o = 8; o > 0; o >>= 1) m = fmaxf(m, __shfl_xor(m, o, 16));
    float pa = __expf(a - m), pb = __expf(bv - m), pc = (jl < 8) ? __expf(cv - m) : 0.f;
    float s = pa + pb + pc;
    #pragma unroll
    for (int o = 8; o > 0; o >>= 1) s += __shfl_xor(s, o, 16);
    float inv = 1.f / s;
    pr[jl] = pa * inv;
    pr[16 + jl] = pb * inv;
    if (jl < 8) pr[32 + jl] = pc * inv;
  }
  __syncthreads();

  // ao partials: 4 rows x 4 quarters x 64 d = 1024
  for (int e = tid; e < 1024; e += 512) {
    const int d = e & 63, qrt = (e >> 6) & 3, br = e >> 8, hh = d >> 3;
    float acc = 0.f;
    #pragma unroll
    for (int k = qrt*10; k < qrt*10 + 10; ++k) {
      int o = ((br*40 + k) << 6) + (d ^ ((k & 7) << 3));
      acc += g0f[br*720 + hh*40 + k] * bf2f(bB1[o]);
    }
    g1f[br*512 + qrt*64 + d] = acc;
  }
  __syncthreads();
  if (tid < 256) {
    float* p = g1f + (tid >> 6)*512;
    int d = tid & 63;
    p[256 + d] = p[d] + p[64 + d] + p[128 + d] + p[192 + d];
  }
  __syncthreads();

  // c = seq0 + ao @ aoW.T + aob
  if (tid < 256) {
    int br = tid >> 6, o = tid & 63;
    g0f[br*720 + 448 + o] = g0f[br*720 + 384 + o] + aob[o]
                          + dotg64(&g1f[br*512 + 256], aoW + (size_t)o*64);
  }
  __syncthreads();

  // MLP1: 4 rows x 128 = 512 exactly
  {
    int br = tid >> 7, o = tid & 127;
    g1f[br*512 + 320 + o] = fmaxf(b1[o] + dotg64(&g0f[br*720 + 448], w1 + (size_t)o*64), 0.f);
  }
  __syncthreads();

  // MLP2
  if (tid < 256) {
    int br = tid >> 6, o = tid & 63;
    float acc = dotg64(&g1f[br*512 + 320], w2 + (size_t)o*128)
              + dotg64(&g1f[br*512 + 384], w2 + (size_t)o*128 + 64);
    g1f[br*512 + 448 + o] = fmaxf(acc + b2[o], 0.f);
  }
  __syncthreads();

  if (tid < 256) {
    int br = tid >> 6;
    float v = g1f[br*512 + 448 + lane] * w3[lane];
    v = wred64(v);
    if (lane == 0) out[b*4 + br] = v + b3[0];
  }
}

extern "C" void kernel_launch(void* const* d_in, const int* in_sizes, int n_in,
                              void* d_out, int out_size, void* d_ws, size_t ws_size,
                              hipStream_t stream) {
  (void)n_in; (void)ws_size; (void)out_size;
  const float* dense_x = (const float*)d_in[0];
  const float* dense_W = (const float*)d_in[1];
  const float* dense_b = (const float*)d_in[2];
  const float* tbl     = (const float*)d_in[3];
  const float* cls     = (const float*)d_in[4];
  const float* ng      = (const float*)d_in[5];
  const float* nb      = (const float*)d_in[6];
  const float* xW      = (const float*)d_in[7];
  const float* xb      = (const float*)d_in[8];
  const float* Ap      = (const float*)d_in[9];
  const float* Dp      = (const float*)d_in[10];
  const float* oW      = (const float*)d_in[11];
  const float* ob      = (const float*)d_in[12];
  const float* mW      = (const float*)d_in[13];
  const float* mb      = (const float*)d_in[14];
  const float* aiW     = (const float*)d_in[15];
  const float* aib     = (const float*)d_in[16];
  const float* aoW     = (const float*)d_in[17];
  const float* aob     = (const float*)d_in[18];
  const float* w1      = (const float*)d_in[19];
  const float* b1      = (const float*)d_in[20];
  const float* w2      = (const float*)d_in[21];
  const float* b2      = (const float*)d_in[22];
  const float* w3      = (const float*)d_in[23];
  const float* b3      = (const float*)d_in[24];
  const int*   sidx    = (const int*)d_in[25];
  float* out = (float*)d_out;
  unsigned short* wsb = (unsigned short*)d_ws;

  hipLaunchKernelGGL(prep_kernel, dim3(256), dim3(256), 0, stream,
                     xW, oW, mW, aiW, Ap, wsb);

  const int B = in_sizes[0] / 13;  // 1024
  hipLaunchKernelGGL(Mamba4CTRV9_kernel, dim3(B/4), dim3(512), 0, stream,
                     dense_x, dense_W, dense_b, tbl, cls, ng, nb, xb, Dp, ob, mb,
                     aib, aoW, aob, w1, b1, w2, b2, w3, b3, sidx, wsb, out);
}